// Round 6
// baseline (196.572 us; speedup 1.0000x reference)
//
#include <hip/hip_runtime.h>

#define NI 8
#define NF 100
#define NH 40
#define NC 40
#define NM 41
#define BSZ 2048
#define BT 64
#define XPAD 104   // x-tile LDS row stride (floats), zero-padded 100..103

typedef __attribute__((ext_vector_type(8))) short bf16x8;
typedef __attribute__((ext_vector_type(4))) float f32x4;
typedef __attribute__((ext_vector_type(4))) unsigned int u32x4;

__device__ __forceinline__ unsigned short f2bf(float f) {
    unsigned int u = __builtin_bit_cast(unsigned int, f);
    u += 0x7fffu + ((u >> 16) & 1u);
    return (unsigned short)(u >> 16);
}
__device__ __forceinline__ float bf2f(unsigned short s) {
    unsigned int u = ((unsigned int)s) << 16;
    return __builtin_bit_cast(float, u);
}
__device__ __forceinline__ bf16x8 pack8(float4 u, float4 v) {
    u32x4 w;
    w.x = (unsigned int)f2bf(u.x) | ((unsigned int)f2bf(u.y) << 16);
    w.y = (unsigned int)f2bf(u.z) | ((unsigned int)f2bf(u.w) << 16);
    w.z = (unsigned int)f2bf(v.x) | ((unsigned int)f2bf(v.y) << 16);
    w.w = (unsigned int)f2bf(v.z) | ((unsigned int)f2bf(v.w) << 16);
    return __builtin_bit_cast(bf16x8, w);
}
// async global->LDS DMA: 64 lanes x 16B; LDS dest = uniform base + lane*16
__device__ __forceinline__ void gl2lds16(const void* g, void* l) {
    __builtin_amdgcn_global_load_lds(
        (const __attribute__((address_space(1))) unsigned int*)g,
        (__attribute__((address_space(3))) unsigned int*)l, 16, 0, 0);
}

// ---------------------------------------------------------------------------
// K1: W_ic = A_ic @ B_ic (fp32), emit bf16 MFMA B-frags (layouts verified R2-R5).
//   Wb1: [ic][nt(3)][k(4)][lane(64)] x16B; n=nt*16+(lane&15), f=k*32+(lane>>4)*8+j
//   Wb2: [ic][nt(7)][kk(2)][lane(64)] x16B; n=nt*16+(lane&15), h=kk*32+(lane>>4)*8+j
// ---------------------------------------------------------------------------
__global__ __launch_bounds__(512) void build_w_kernel(
    const float* __restrict__ A, const float* __restrict__ Bp,
    unsigned short* __restrict__ Wb1, unsigned short* __restrict__ Wb2)
{
    __shared__ __align__(16) float As[NF * NM];
    __shared__ __align__(16) float Bs[NM * NH];
    __shared__ __align__(16) float Ws[NF * NH];
    const int ic = blockIdx.x;
    const float* Ap  = A  + (size_t)ic * NF * NM;
    const float* Bpp = Bp + (size_t)ic * NM * NH;
    for (int idx = threadIdx.x; idx < NF * NM; idx += 512) As[idx] = Ap[idx];
    for (int idx = threadIdx.x; idx < NM * NH; idx += 512) Bs[idx] = Bpp[idx];
    __syncthreads();
    for (int idx = threadIdx.x; idx < NF * (NH / 4); idx += 512) {
        const int f  = idx / (NH / 4);
        const int hq = idx % (NH / 4);
        float4 acc = make_float4(0.f, 0.f, 0.f, 0.f);
        #pragma unroll
        for (int m = 0; m < NM; ++m) {
            const float  a = As[f * NM + m];
            const float4 b = *(const float4*)&Bs[m * NH + hq * 4];
            acc.x += a * b.x; acc.y += a * b.y; acc.z += a * b.z; acc.w += a * b.w;
        }
        *(float4*)&Ws[f * NH + hq * 4] = acc;
    }
    __syncthreads();

    for (int e = threadIdx.x; e < 768; e += 512) {
        const int nt = e >> 8, k = (e >> 6) & 3, ln = e & 63;
        const int colx = ln & 15, quad = ln >> 4;
        const int h = nt * 16 + colx;
        unsigned int w[4];
        #pragma unroll
        for (int jj = 0; jj < 4; ++jj) {
            const int f0 = k * 32 + quad * 8 + jj * 2;
            const int f1 = f0 + 1;
            const unsigned int lo = (f0 < NF && h < NH) ? f2bf(Ws[f0 * NH + h]) : 0;
            const unsigned int hi = (f1 < NF && h < NH) ? f2bf(Ws[f1 * NH + h]) : 0;
            w[jj] = lo | (hi << 16);
        }
        ((u32x4*)Wb1)[(size_t)ic * 768 + e] = (u32x4){w[0], w[1], w[2], w[3]};
    }
    for (int e = threadIdx.x; e < 896; e += 512) {
        const int nt = e >> 7, kk = (e >> 6) & 1, ln = e & 63;
        const int colx = ln & 15, quad = ln >> 4;
        const int f = nt * 16 + colx;
        unsigned int w[4];
        #pragma unroll
        for (int jj = 0; jj < 4; ++jj) {
            const int h0 = kk * 32 + quad * 8 + jj * 2;
            const int h1 = h0 + 1;
            const unsigned int lo = (f < NF && h0 < NH) ? f2bf(Ws[f * NH + h0]) : 0;
            const unsigned int hi = (f < NF && h1 < NH) ? f2bf(Ws[f * NH + h1]) : 0;
            w[jj] = lo | (hi << 16);
        }
        ((u32x4*)Wb2)[(size_t)ic * 896 + e] = (u32x4){w[0], w[1], w[2], w[3]};
    }
}

// ---------------------------------------------------------------------------
// Fused MFMA kernel v2: async global_load_lds double-buffered B-frag pipeline,
// 2 c's per super-iter, fixed per-wave tile ownership (no cross-wave reduces).
// pass1 tiles t=mt*3+nt (12): wave w owns {w, w+8}. pass2 tiles t=mt*7+nt (28):
// wave w owns {t : t%8==w}. Each tile accumulated over all c by its owner.
// ---------------------------------------------------------------------------
__global__ __launch_bounds__(512, 1) void fused_kernel(
    const float* __restrict__ x, const float* __restrict__ mask,
    const float* __restrict__ b_final,
    const unsigned short* __restrict__ Wb1, const unsigned short* __restrict__ Wb2,
    float* __restrict__ out)
{
    __shared__ unsigned char msx[BT * NC];                 // 2560 B
    __shared__ __align__(16) float xs[BT * XPAD];          // 26624 B
    __shared__ __align__(16) unsigned char wbuf[2 * 28672];// 57344 B (p1: 2x24576)
    __shared__ __align__(16) unsigned short hs[64 * 72];   // 9216 B, stride 72

    const int tid  = threadIdx.x;
    const int lane = tid & 63;
    const int wav  = tid >> 6;       // 0..7
    const int col  = lane & 15;
    const int quad = lane >> 4;
    const int i    = blockIdx.x % NI;
    const int b0   = (blockIdx.x / NI) * BT;

    const unsigned char* wb1B = (const unsigned char*)Wb1 + (size_t)i * NC * 12288;
    const unsigned char* wb2B = (const unsigned char*)Wb2 + (size_t)i * NC * 14336;

    // ---- prefetch pass1 super-iter 0 (c=0,1) into buf0: 24 x 1KB entries ----
    #pragma unroll
    for (int j = 0; j < 3; ++j) {
        const int e = wav * 3 + j, cj = e / 12, ee = e % 12;
        gl2lds16(wb1B + (size_t)cj * 12288 + ee * 1024 + lane * 16,
                 wbuf + cj * 12288 + ee * 1024);
    }

    // ---- stage mask (bytes), x tile (float4), zero hs ----
    for (int idx = tid; idx < BT * NC; idx += 512) {
        const int b = idx / NC, c = idx % NC;
        msx[idx] = mask[((size_t)(b0 + b) * NI + i) * NC + c] > 0.5f ? 1 : 0;
    }
    for (int idx = tid; idx < BT * (XPAD / 4); idx += 512) {
        const int row = idx / (XPAD / 4), fq = idx % (XPAD / 4);
        float4 v = make_float4(0.f, 0.f, 0.f, 0.f);
        if (fq < NF / 4)
            v = *(const float4*)(x + ((size_t)(b0 + row) * NI + i) * NF + fq * 4);
        *(float4*)&xs[row * XPAD + fq * 4] = v;
    }
    for (int idx = tid; idx < 64 * 72 / 2; idx += 512) ((unsigned int*)hs)[idx] = 0;
    __syncthreads();   // xs/msx/hs ready; drains prefetch(0)

    // ---- build X A-frags: a1[mt][k], M=64, K=128(pad) ----
    bf16x8 a1[4][4];
    #pragma unroll
    for (int mt = 0; mt < 4; ++mt) {
        const float* xr = xs + (mt * 16 + col) * XPAD;
        #pragma unroll
        for (int k = 0; k < 4; ++k) {
            if (k < 3 || quad == 0) {
                const float4 u = *(const float4*)(xr + k * 32 + quad * 8);
                const float4 v = *(const float4*)(xr + k * 32 + quad * 8 + 4);
                a1[mt][k] = pack8(u, v);
            } else {
                a1[mt][k] = __builtin_bit_cast(bf16x8, (u32x4){0, 0, 0, 0});
            }
        }
    }
    __syncthreads();   // all waves done with xs

    // ---- pass 1: 20 super-iters x 2 c; owner tiles accumulate over all c ----
    f32x4 Ht[2];
    Ht[0] = (f32x4){0.f, 0.f, 0.f, 0.f};
    Ht[1] = (f32x4){0.f, 0.f, 0.f, 0.f};
    #pragma unroll 1
    for (int s = 0; s < 20; ++s) {
        if (s < 19) {   // prefetch s+1 into other buffer
            const int c0n = 2 * (s + 1);
            #pragma unroll
            for (int j = 0; j < 3; ++j) {
                const int e = wav * 3 + j, cj = e / 12, ee = e % 12;
                gl2lds16(wb1B + (size_t)(c0n + cj) * 12288 + ee * 1024 + lane * 16,
                         wbuf + ((s + 1) & 1) * 24576 + cj * 12288 + ee * 1024);
            }
        }
        const unsigned char* bs = wbuf + (s & 1) * 24576;
        #pragma unroll
        for (int cj = 0; cj < 2; ++cj) {
            const int c = 2 * s + cj;
            const unsigned char* bb = bs + cj * 12288;
            #pragma unroll
            for (int j = 0; j < 2; ++j) {
                if (j == 1 && wav >= 4) continue;   // waves 4-7 own 1 tile
                const int t = wav + 8 * j;
                const int mt = t / 3, nt = t % 3;
                f32x4 P = (f32x4){0.f, 0.f, 0.f, 0.f};
                #pragma unroll
                for (int k = 0; k < 4; ++k)
                    P = __builtin_amdgcn_mfma_f32_16x16x32_bf16(
                        a1[mt][k],
                        *(const bf16x8*)(bb + (nt * 4 + k) * 1024 + (size_t)lane * 16),
                        P, 0, 0, 0);
                #pragma unroll
                for (int r = 0; r < 4; ++r)
                    Ht[j][r] += (float)msx[(mt * 16 + quad * 4 + r) * NC + c] * P[r];
            }
        }
        __syncthreads();   // drains prefetch; protects buffers
    }

    // ---- prefetch pass2 super-iter 0 (c=0,1) into buf0 (28 x 1KB) ----
    const int cnt2 = (wav < 4) ? 4 : 3;
    const int eb2  = (wav < 4) ? wav * 4 : 16 + (wav - 4) * 3;
    #pragma unroll
    for (int j = 0; j < 4; ++j) {
        if (j >= cnt2) break;
        const int e = eb2 + j, cj = e / 14, ee = e % 14;
        gl2lds16(wb2B + (size_t)cj * 14336 + ee * 1024 + lane * 16,
                 wbuf + cj * 14336 + ee * 1024);
    }

    // ---- owners write complete H tiles (bf16) into hs ----
    #pragma unroll
    for (int j = 0; j < 2; ++j) {
        if (j == 1 && wav >= 4) continue;
        const int t = wav + 8 * j;
        const int mt = t / 3, nt = t % 3;
        #pragma unroll
        for (int r = 0; r < 4; ++r)
            hs[(mt * 16 + quad * 4 + r) * 72 + nt * 16 + col] = f2bf(Ht[j][r]);
    }
    __syncthreads();   // hs visible; drains pass2 prefetch(0)

    // ---- build pass2 A-frags for all 4 mt: K=40 pad 64 (cols 40..63 = 0) ----
    bf16x8 a2[4][2];
    #pragma unroll
    for (int mt = 0; mt < 4; ++mt)
        #pragma unroll
        for (int kk = 0; kk < 2; ++kk)
            a2[mt][kk] = *(const bf16x8*)&hs[(mt * 16 + col) * 72 + kk * 32 + quad * 8];

    // ---- pass 2: 20 super-iters x 2 c; owned tiles t%8==wav ----
    f32x4 Ot[4];
    #pragma unroll
    for (int j = 0; j < 4; ++j) Ot[j] = (f32x4){0.f, 0.f, 0.f, 0.f};
    #pragma unroll 1
    for (int s = 0; s < 20; ++s) {
        if (s < 19) {
            const int c0n = 2 * (s + 1);
            #pragma unroll
            for (int j = 0; j < 4; ++j) {
                if (j >= cnt2) break;
                const int e = eb2 + j, cj = e / 14, ee = e % 14;
                gl2lds16(wb2B + (size_t)(c0n + cj) * 14336 + ee * 1024 + lane * 16,
                         wbuf + ((s + 1) & 1) * 28672 + cj * 14336 + ee * 1024);
            }
        }
        const unsigned char* bs = wbuf + (s & 1) * 28672;
        #pragma unroll
        for (int cj = 0; cj < 2; ++cj) {
            const int c = 2 * s + cj;
            const unsigned char* bb = bs + cj * 14336;
            #pragma unroll
            for (int j = 0; j < 4; ++j) {
                if (j >= cnt2) continue;
                const int t = wav + 8 * j;
                const int mt = t / 7, nt = t % 7;
                f32x4 P = (f32x4){0.f, 0.f, 0.f, 0.f};
                P = __builtin_amdgcn_mfma_f32_16x16x32_bf16(
                    a2[mt][0], *(const bf16x8*)(bb + (nt * 2 + 0) * 1024 + (size_t)lane * 16),
                    P, 0, 0, 0);
                P = __builtin_amdgcn_mfma_f32_16x16x32_bf16(
                    a2[mt][1], *(const bf16x8*)(bb + (nt * 2 + 1) * 1024 + (size_t)lane * 16),
                    P, 0, 0, 0);
                #pragma unroll
                for (int r = 0; r < 4; ++r)
                    Ot[j][r] += (float)msx[(mt * 16 + quad * 4 + r) * NC + c] * P[r];
            }
        }
        __syncthreads();
    }

    // ---- epilogue: bias + relu, store straight from accumulators ----
    #pragma unroll
    for (int j = 0; j < 4; ++j) {
        if (j >= cnt2) continue;
        const int t = wav + 8 * j;
        const int mt = t / 7, nt = t % 7;
        const int f = nt * 16 + col;
        if (f < NF) {
            const float bias = b_final[i * NF + f];
            #pragma unroll
            for (int r = 0; r < 4; ++r) {
                const int b = b0 + mt * 16 + quad * 4 + r;
                out[((size_t)b * NI + i) * NF + f] = fmaxf(Ot[j][r] + bias, 0.f);
            }
        }
    }
}

extern "C" void kernel_launch(void* const* d_in, const int* in_sizes, int n_in,
                              void* d_out, int out_size, void* d_ws, size_t ws_size,
                              hipStream_t stream) {
    const float* x       = (const float*)d_in[0];  // (2048, 8, 100)
    const float* tk_mask = (const float*)d_in[1];  // (2048, 8, 40)
    const float* A       = (const float*)d_in[2];  // (8, 40, 100, 41)
    const float* Bp      = (const float*)d_in[3];  // (8, 40, 41, 40)
    const float* b_final = (const float*)d_in[4];  // (8, 100)
    float* out = (float*)d_out;                    // (2048, 8, 100)

    unsigned short* Wb1 = (unsigned short*)d_ws;
    unsigned short* Wb2 = Wb1 + (size_t)NI * NC * 768 * 8;

    build_w_kernel<<<NI * NC, 512, 0, stream>>>(A, Bp, Wb1, Wb2);
    fused_kernel<<<(BSZ / BT) * NI, 512, 0, stream>>>(x, tk_mask, b_final, Wb1, Wb2, out);
}

// Round 7
// 120.508 us; speedup vs baseline: 1.6312x; 1.6312x over previous
//
#include <hip/hip_runtime.h>

#define NI 8
#define NF 100
#define NH 40
#define NC 40
#define NM 41
#define BSZ 2048
#define BT 64
#define XPAD 104   // x-tile LDS row stride (floats), zero-padded 100..103

typedef __attribute__((ext_vector_type(8))) short bf16x8;
typedef __attribute__((ext_vector_type(4))) float f32x4;
typedef __attribute__((ext_vector_type(4))) unsigned int u32x4;

__device__ __forceinline__ unsigned short f2bf(float f) {
    unsigned int u = __builtin_bit_cast(unsigned int, f);
    u += 0x7fffu + ((u >> 16) & 1u);
    return (unsigned short)(u >> 16);
}
__device__ __forceinline__ bf16x8 pack8(float4 u, float4 v) {
    u32x4 w;
    w.x = (unsigned int)f2bf(u.x) | ((unsigned int)f2bf(u.y) << 16);
    w.y = (unsigned int)f2bf(u.z) | ((unsigned int)f2bf(u.w) << 16);
    w.z = (unsigned int)f2bf(v.x) | ((unsigned int)f2bf(v.y) << 16);
    w.w = (unsigned int)f2bf(v.z) | ((unsigned int)f2bf(v.w) << 16);
    return __builtin_bit_cast(bf16x8, w);
}
// async global->LDS DMA: 64 lanes x 16B; LDS dest = wave-uniform base + lane*16
__device__ __forceinline__ void gl2lds16(const void* g, void* l) {
    __builtin_amdgcn_global_load_lds(
        (const __attribute__((address_space(1))) unsigned int*)g,
        (__attribute__((address_space(3))) unsigned int*)l, 16, 0, 0);
}

// ---------------------------------------------------------------------------
// K1: W_ic = A_ic @ B_ic (fp32), emit bf16 MFMA B-frags (layouts verified R2-R6).
//   Wb1: [ic][nt(3)][k(4)][lane(64)] x16B; n=nt*16+(lane&15), f=k*32+(lane>>4)*8+j
//   Wb2: [ic][nt(7)][kk(2)][lane(64)] x16B; n=nt*16+(lane&15), h=kk*32+(lane>>4)*8+j
// ---------------------------------------------------------------------------
__global__ __launch_bounds__(512) void build_w_kernel(
    const float* __restrict__ A, const float* __restrict__ Bp,
    unsigned short* __restrict__ Wb1, unsigned short* __restrict__ Wb2)
{
    __shared__ __align__(16) float As[NF * NM];
    __shared__ __align__(16) float Bs[NM * NH];
    __shared__ __align__(16) float Ws[NF * NH];
    const int ic = blockIdx.x;
    const float* Ap  = A  + (size_t)ic * NF * NM;
    const float* Bpp = Bp + (size_t)ic * NM * NH;
    for (int idx = threadIdx.x; idx < NF * NM; idx += 512) As[idx] = Ap[idx];
    for (int idx = threadIdx.x; idx < NM * NH; idx += 512) Bs[idx] = Bpp[idx];
    __syncthreads();
    for (int idx = threadIdx.x; idx < NF * (NH / 4); idx += 512) {
        const int f  = idx / (NH / 4);
        const int hq = idx % (NH / 4);
        float4 acc = make_float4(0.f, 0.f, 0.f, 0.f);
        #pragma unroll
        for (int m = 0; m < NM; ++m) {
            const float  a = As[f * NM + m];
            const float4 b = *(const float4*)&Bs[m * NH + hq * 4];
            acc.x += a * b.x; acc.y += a * b.y; acc.z += a * b.z; acc.w += a * b.w;
        }
        *(float4*)&Ws[f * NH + hq * 4] = acc;
    }
    __syncthreads();

    for (int e = threadIdx.x; e < 768; e += 512) {
        const int nt = e >> 8, k = (e >> 6) & 3, ln = e & 63;
        const int colx = ln & 15, quad = ln >> 4;
        const int h = nt * 16 + colx;
        unsigned int w[4];
        #pragma unroll
        for (int jj = 0; jj < 4; ++jj) {
            const int f0 = k * 32 + quad * 8 + jj * 2;
            const int f1 = f0 + 1;
            const unsigned int lo = (f0 < NF && h < NH) ? f2bf(Ws[f0 * NH + h]) : 0;
            const unsigned int hi = (f1 < NF && h < NH) ? f2bf(Ws[f1 * NH + h]) : 0;
            w[jj] = lo | (hi << 16);
        }
        ((u32x4*)Wb1)[(size_t)ic * 768 + e] = (u32x4){w[0], w[1], w[2], w[3]};
    }
    for (int e = threadIdx.x; e < 896; e += 512) {
        const int nt = e >> 7, kk = (e >> 6) & 1, ln = e & 63;
        const int colx = ln & 15, quad = ln >> 4;
        const int f = nt * 16 + colx;
        unsigned int w[4];
        #pragma unroll
        for (int jj = 0; jj < 4; ++jj) {
            const int h0 = kk * 32 + quad * 8 + jj * 2;
            const int h1 = h0 + 1;
            const unsigned int lo = (f < NF && h0 < NH) ? f2bf(Ws[f * NH + h0]) : 0;
            const unsigned int hi = (f < NF && h1 < NH) ? f2bf(Ws[f * NH + h1]) : 0;
            w[jj] = lo | (hi << 16);
        }
        ((u32x4*)Wb2)[(size_t)ic * 896 + e] = (u32x4){w[0], w[1], w[2], w[3]};
    }
}

// ---------------------------------------------------------------------------
// Fused MFMA kernel v3 (= v2 structure, scratch-free).
// R6 bug: register arrays indexed by runtime (wav-derived) mt -> LLVM demoted
// them to scratch (VGPR_Count 88, 33 MB scratch writes). Fix: each wave builds
// ONLY its own tiles' A-frags; register arrays indexed by unrolled literals;
// runtime mt/nt used in LDS addresses only. No break/continue in unrolled loops.
// LDS: x-tile aliased onto pipeline buffer 1 -> 67.5 KB -> 2 blocks/CU.
// ---------------------------------------------------------------------------
__global__ __launch_bounds__(512, 2) void fused_kernel(
    const float* __restrict__ x, const float* __restrict__ mask,
    const float* __restrict__ b_final,
    const unsigned short* __restrict__ Wb1, const unsigned short* __restrict__ Wb2,
    float* __restrict__ out)
{
    // smem map: [0,28672) buf0 | [28672,57344) buf1 (aliases x-tile)
    //           [57344,66560) hs (64 rows x 72 bf16) | [66560,69120) msx
    __shared__ __align__(16) unsigned char smem[2 * 28672 + 9216 + BT * NC];
    unsigned char* wbuf = smem;
    float* xs = (float*)(smem + 28672);          // dead before buf1 first written
    unsigned short* hs = (unsigned short*)(smem + 2 * 28672);
    unsigned char* msx = smem + 2 * 28672 + 9216;

    const int tid  = threadIdx.x;
    const int lane = tid & 63;
    const int wav  = tid >> 6;       // 0..7
    const int col  = lane & 15;
    const int quad = lane >> 4;
    const int i    = blockIdx.x % NI;
    const int b0   = (blockIdx.x / NI) * BT;

    const unsigned char* wb1B = (const unsigned char*)Wb1 + (size_t)i * NC * 12288;
    const unsigned char* wb2B = (const unsigned char*)Wb2 + (size_t)i * NC * 14336;

    // pass1 tile ownership: 12 tiles t=mt*3+nt; wave w owns t0=w, (w<4) t1=w+8
    const int mt0 = wav / 3, nt0 = wav % 3;
    const int mt1 = (wav + 8) / 3, nt1 = (wav + 8) % 3;   // valid only wav<4
    const bool own1 = (wav < 4);

    // ---- prefetch pass1 super-iter 0 (c=0,1) into buf0: 24 x 1KB entries ----
    #pragma unroll
    for (int j = 0; j < 3; ++j) {
        const int e = wav * 3 + j, cj = e / 12, ee = e % 12;
        gl2lds16(wb1B + (size_t)cj * 12288 + ee * 1024 + lane * 16,
                 wbuf + cj * 12288 + ee * 1024);
    }

    // ---- stage mask (bytes), x tile (float4, into buf1 space), zero hs ----
    for (int idx = tid; idx < BT * NC; idx += 512) {
        const int b = idx / NC, c = idx % NC;
        msx[idx] = mask[((size_t)(b0 + b) * NI + i) * NC + c] > 0.5f ? 1 : 0;
    }
    for (int idx = tid; idx < BT * (XPAD / 4); idx += 512) {
        const int row = idx / (XPAD / 4), fq = idx % (XPAD / 4);
        float4 v = make_float4(0.f, 0.f, 0.f, 0.f);
        if (fq < NF / 4)
            v = *(const float4*)(x + ((size_t)(b0 + row) * NI + i) * NF + fq * 4);
        *(float4*)&xs[row * XPAD + fq * 4] = v;
    }
    for (int idx = tid; idx < 64 * 72 / 2; idx += 512) ((unsigned int*)hs)[idx] = 0;
    __syncthreads();   // xs/msx/hs ready; drains prefetch(0)

    // ---- build ONLY this wave's A-frags (literal indices; runtime mt in addr) ----
    bf16x8 A0[4], A1[4];
    {
        const float* xr0 = xs + (mt0 * 16 + col) * XPAD;
        const float* xr1 = xs + (mt1 * 16 + col) * XPAD;
        #pragma unroll
        for (int k = 0; k < 4; ++k) {
            if (k < 3 || quad == 0) {
                A0[k] = pack8(*(const float4*)(xr0 + k * 32 + quad * 8),
                              *(const float4*)(xr0 + k * 32 + quad * 8 + 4));
            } else {
                A0[k] = __builtin_bit_cast(bf16x8, (u32x4){0, 0, 0, 0});
            }
            A1[k] = __builtin_bit_cast(bf16x8, (u32x4){0, 0, 0, 0});
            if (own1 && (k < 3 || quad == 0)) {
                A1[k] = pack8(*(const float4*)(xr1 + k * 32 + quad * 8),
                              *(const float4*)(xr1 + k * 32 + quad * 8 + 4));
            }
        }
    }
    __syncthreads();   // all waves done with xs; buf1 may now be overwritten

    // ---- pass 1: 20 super-iters x 2 c ----
    f32x4 Ht0 = (f32x4){0.f, 0.f, 0.f, 0.f};
    f32x4 Ht1 = (f32x4){0.f, 0.f, 0.f, 0.f};
    #pragma unroll 1
    for (int s = 0; s < 20; ++s) {
        if (s < 19) {   // prefetch s+1 into other buffer
            const int c0n = 2 * (s + 1);
            #pragma unroll
            for (int j = 0; j < 3; ++j) {
                const int e = wav * 3 + j, cj = e / 12, ee = e % 12;
                gl2lds16(wb1B + (size_t)(c0n + cj) * 12288 + ee * 1024 + lane * 16,
                         wbuf + ((s + 1) & 1) * 28672 + cj * 12288 + ee * 1024);
            }
        }
        const unsigned char* bs = wbuf + (s & 1) * 28672;
        #pragma unroll
        for (int cj = 0; cj < 2; ++cj) {
            const int c = 2 * s + cj;
            const unsigned char* bb = bs + cj * 12288;
            {   // tile t0
                f32x4 P = (f32x4){0.f, 0.f, 0.f, 0.f};
                #pragma unroll
                for (int k = 0; k < 4; ++k)
                    P = __builtin_amdgcn_mfma_f32_16x16x32_bf16(
                        A0[k],
                        *(const bf16x8*)(bb + (nt0 * 4 + k) * 1024 + (size_t)lane * 16),
                        P, 0, 0, 0);
                #pragma unroll
                for (int r = 0; r < 4; ++r)
                    Ht0[r] += (float)msx[(mt0 * 16 + quad * 4 + r) * NC + c] * P[r];
            }
            if (own1) {   // tile t1
                f32x4 P = (f32x4){0.f, 0.f, 0.f, 0.f};
                #pragma unroll
                for (int k = 0; k < 4; ++k)
                    P = __builtin_amdgcn_mfma_f32_16x16x32_bf16(
                        A1[k],
                        *(const bf16x8*)(bb + (nt1 * 4 + k) * 1024 + (size_t)lane * 16),
                        P, 0, 0, 0);
                #pragma unroll
                for (int r = 0; r < 4; ++r)
                    Ht1[r] += (float)msx[(mt1 * 16 + quad * 4 + r) * NC + c] * P[r];
            }
        }
        __syncthreads();   // drains prefetch; protects buffers
    }

    // ---- prefetch pass2 super-iter 0 (c=0,1) into buf0 (28 x 1KB) ----
    const int cnt2 = (wav < 4) ? 4 : 3;
    const int eb2  = (wav < 4) ? wav * 4 : 16 + (wav - 4) * 3;
    #pragma unroll
    for (int j = 0; j < 4; ++j) {
        if (j < cnt2) {
            const int e = eb2 + j, cj = e / 14, ee = e % 14;
            gl2lds16(wb2B + (size_t)cj * 14336 + ee * 1024 + lane * 16,
                     wbuf + cj * 14336 + ee * 1024);
        }
    }

    // ---- owners write complete H tiles (bf16) into hs ----
    #pragma unroll
    for (int r = 0; r < 4; ++r)
        hs[(mt0 * 16 + quad * 4 + r) * 72 + nt0 * 16 + col] = f2bf(Ht0[r]);
    if (own1) {
        #pragma unroll
        for (int r = 0; r < 4; ++r)
            hs[(mt1 * 16 + quad * 4 + r) * 72 + nt1 * 16 + col] = f2bf(Ht1[r]);
    }
    __syncthreads();   // hs visible; drains pass2 prefetch(0)

    // ---- pass2 A-frags: 4 owned tiles, literal j/kk indices, runtime mt in addr
    // K=40 padded 64: hs cols 40..63 zero (zero-init, pass1 writes cols<48=0 there)
    bf16x8 A2[4][2];
    #pragma unroll
    for (int j = 0; j < 4; ++j) {
        #pragma unroll
        for (int kk = 0; kk < 2; ++kk)
            A2[j][kk] = __builtin_bit_cast(bf16x8, (u32x4){0, 0, 0, 0});
        if (j < cnt2) {
            const int t = wav + 8 * j;
            const int mt = t / 7;
            #pragma unroll
            for (int kk = 0; kk < 2; ++kk)
                A2[j][kk] = *(const bf16x8*)&hs[(mt * 16 + col) * 72 + kk * 32 + quad * 8];
        }
    }

    // ---- pass 2: 20 super-iters x 2 c; owned tiles t = wav + 8j ----
    f32x4 Ot[4];
    #pragma unroll
    for (int j = 0; j < 4; ++j) Ot[j] = (f32x4){0.f, 0.f, 0.f, 0.f};
    #pragma unroll 1
    for (int s = 0; s < 20; ++s) {
        if (s < 19) {
            const int c0n = 2 * (s + 1);
            #pragma unroll
            for (int j = 0; j < 4; ++j) {
                if (j < cnt2) {
                    const int e = eb2 + j, cj = e / 14, ee = e % 14;
                    gl2lds16(wb2B + (size_t)(c0n + cj) * 14336 + ee * 1024 + lane * 16,
                             wbuf + ((s + 1) & 1) * 28672 + cj * 14336 + ee * 1024);
                }
            }
        }
        const unsigned char* bs = wbuf + (s & 1) * 28672;
        #pragma unroll
        for (int cj = 0; cj < 2; ++cj) {
            const int c = 2 * s + cj;
            const unsigned char* bb = bs + cj * 14336;
            #pragma unroll
            for (int j = 0; j < 4; ++j) {
                if (j < cnt2) {
                    const int t = wav + 8 * j;
                    const int mt = t / 7, nt = t % 7;
                    f32x4 P = (f32x4){0.f, 0.f, 0.f, 0.f};
                    P = __builtin_amdgcn_mfma_f32_16x16x32_bf16(
                        A2[j][0],
                        *(const bf16x8*)(bb + (nt * 2 + 0) * 1024 + (size_t)lane * 16),
                        P, 0, 0, 0);
                    P = __builtin_amdgcn_mfma_f32_16x16x32_bf16(
                        A2[j][1],
                        *(const bf16x8*)(bb + (nt * 2 + 1) * 1024 + (size_t)lane * 16),
                        P, 0, 0, 0);
                    #pragma unroll
                    for (int r = 0; r < 4; ++r)
                        Ot[j][r] += (float)msx[(mt * 16 + quad * 4 + r) * NC + c] * P[r];
                }
            }
        }
        __syncthreads();
    }

    // ---- epilogue: bias + relu, store straight from accumulators ----
    #pragma unroll
    for (int j = 0; j < 4; ++j) {
        if (j < cnt2) {
            const int t = wav + 8 * j;
            const int mt = t / 7, nt = t % 7;
            const int f = nt * 16 + col;
            if (f < NF) {
                const float bias = b_final[i * NF + f];
                #pragma unroll
                for (int r = 0; r < 4; ++r) {
                    const int b = b0 + mt * 16 + quad * 4 + r;
                    out[((size_t)b * NI + i) * NF + f] = fmaxf(Ot[j][r] + bias, 0.f);
                }
            }
        }
    }
}

extern "C" void kernel_launch(void* const* d_in, const int* in_sizes, int n_in,
                              void* d_out, int out_size, void* d_ws, size_t ws_size,
                              hipStream_t stream) {
    const float* x       = (const float*)d_in[0];  // (2048, 8, 100)
    const float* tk_mask = (const float*)d_in[1];  // (2048, 8, 40)
    const float* A       = (const float*)d_in[2];  // (8, 40, 100, 41)
    const float* Bp      = (const float*)d_in[3];  // (8, 40, 41, 40)
    const float* b_final = (const float*)d_in[4];  // (8, 100)
    float* out = (float*)d_out;                    // (2048, 8, 100)

    unsigned short* Wb1 = (unsigned short*)d_ws;
    unsigned short* Wb2 = Wb1 + (size_t)NI * NC * 768 * 8;

    build_w_kernel<<<NI * NC, 512, 0, stream>>>(A, Bp, Wb1, Wb2);
    fused_kernel<<<(BSZ / BT) * NI, 512, 0, stream>>>(x, tk_mask, b_final, Wb1, Wb2, out);
}